// Round 1
// baseline (362.546 us; speedup 1.0000x reference)
//
#include <hip/hip_runtime.h>

// PolarQuant: y = FWHT(x*signs)/sqrt(D); idx = searchsorted(mid(centroids), y);
// x_hat = FWHT(centroids[idx])/sqrt(D) * signs.
// D=128, BATCH=262144, K=16.
// Layout: d_out[0 .. B*D)        = x_hat (f32)
//         d_out[B*D .. 2*B*D)    = indices stored as float values (harness reads
//                                  the concatenated tuple as one f32 buffer).

#define D_DIM 128
#define BATCH_N 262144
#define K_LVL 16

// 1/sqrt(128) — float32 of the double 1.0/np.sqrt(128.0), matching the reference.
#define INV_SQRT_D 0.08838834764831843f

__global__ __launch_bounds__(256, 8) void polar_quant_kernel(
    const float* __restrict__ x,      // [BATCH, D]
    const float* __restrict__ signs,  // [D]
    const float* __restrict__ cent,   // [K]
    float* __restrict__ out)          // [2*BATCH*D]
{
    __shared__ float s_cent[K_LVL];
    const int tid = threadIdx.x;
    if (tid < K_LVL) s_cent[tid] = cent[tid];

    // Boundaries: b[j] = 0.5f*(c[j]+c[j+1]) — same f32 op order as the reference.
    // Statically indexed -> stays in registers (uniform; likely SGPR-fed compares).
    float b[K_LVL - 1];
#pragma unroll
    for (int j = 0; j < K_LVL - 1; ++j) b[j] = 0.5f * (cent[j] + cent[j + 1]);

    const int lane = tid & 63;
    const int waves_per_block = blockDim.x >> 6;
    const int global_wave = blockIdx.x * waves_per_block + (tid >> 6);
    const int total_waves = gridDim.x * waves_per_block;

    // Per-lane signs for elements 2l, 2l+1 (uniform across rows; L1/L2 cached).
    const float2 sg = *reinterpret_cast<const float2*>(signs + 2 * lane);

    __syncthreads();

    for (int row = global_wave; row < BATCH_N; row += total_waves) {
        const size_t base = (size_t)row * D_DIM + 2 * lane;
        float2 v = *reinterpret_cast<const float2*>(x + base);

        // rotate: x * signs (exact, +-1), then FWHT, then * 1/sqrt(D)
        float e0 = v.x * sg.x;
        float e1 = v.y * sg.y;
        // stage h=1 (lane-local pair)
        {
            float a = e0 + e1, s = e0 - e1;
            e0 = a; e1 = s;
        }
        // stages h=2..64: partner lane = lane ^ (h/2); lower half: a+b, upper: a-b
#pragma unroll
        for (int m = 1; m <= 32; m <<= 1) {
            float o0 = __shfl_xor(e0, m, 64);
            float o1 = __shfl_xor(e1, m, 64);
            const bool lower = (lane & m) == 0;
            e0 = lower ? (e0 + o0) : (o0 - e0);
            e1 = lower ? (e1 + o1) : (o1 - e1);
        }
        const float y0 = e0 * INV_SQRT_D;
        const float y1 = e1 * INV_SQRT_D;

        // searchsorted(boundaries, y, side='left') == #{ b_j < y }
        int i0 = 0, i1 = 0;
#pragma unroll
        for (int j = 0; j < K_LVL - 1; ++j) {
            i0 += (y0 > b[j]) ? 1 : 0;
            i1 += (y1 > b[j]) ? 1 : 0;
        }

        // centroid gather via LDS (dynamic index; register array would spill)
        float q0 = s_cent[i0];
        float q1 = s_cent[i1];

        // unrotate: FWHT, * 1/sqrt(D), * signs
        {
            float a = q0 + q1, s = q0 - q1;
            q0 = a; q1 = s;
        }
#pragma unroll
        for (int m = 1; m <= 32; m <<= 1) {
            float o0 = __shfl_xor(q0, m, 64);
            float o1 = __shfl_xor(q1, m, 64);
            const bool lower = (lane & m) == 0;
            q0 = lower ? (q0 + o0) : (o0 - q0);
            q1 = lower ? (q1 + o1) : (o1 - q1);
        }

        float2 xo;
        xo.x = q0 * INV_SQRT_D * sg.x;
        xo.y = q1 * INV_SQRT_D * sg.y;
        *reinterpret_cast<float2*>(out + base) = xo;

        float2 io;
        io.x = (float)i0;
        io.y = (float)i1;
        *reinterpret_cast<float2*>(out + (size_t)BATCH_N * D_DIM + base) = io;
    }
}

extern "C" void kernel_launch(void* const* d_in, const int* in_sizes, int n_in,
                              void* d_out, int out_size, void* d_ws, size_t ws_size,
                              hipStream_t stream) {
    const float* x     = (const float*)d_in[0];
    const float* signs = (const float*)d_in[1];
    const float* cent  = (const float*)d_in[2];
    float* out = (float*)d_out;

    // 2048 blocks x 256 threads = 8192 waves (8 blocks/CU on 256 CUs, full
    // occupancy); each wave grid-strides over 32 rows.
    dim3 grid(2048), block(256);
    hipLaunchKernelGGL(polar_quant_kernel, grid, block, 0, stream,
                       x, signs, cent, out);
}